// Round 1
// baseline (1048.428 us; speedup 1.0000x reference)
//
#include <hip/hip_runtime.h>

typedef unsigned int uint32;
typedef unsigned short u16;

#define NPIX (512*512)
#define NWG 2048
#define TPW 2   // NWG*TPW*64 == NPIX

typedef __bf16 v8bf __attribute__((ext_vector_type(8)));
typedef float v4f __attribute__((ext_vector_type(4)));

__device__ __forceinline__ float bl(uint32 u){ return __uint_as_float(u << 16); }
__device__ __forceinline__ float bh(uint32 u){ return __uint_as_float(u & 0xffff0000u); }
__device__ __forceinline__ u16 f2b(float f){
  uint32 u = __float_as_uint(f);
  u += 0x7fffu + ((u >> 16) & 1u);   // round-to-nearest-even
  return (u16)(u >> 16);
}

// Precompute fused weights (fp32 in, bf16 out) into workspace:
//   wqk[hc][i]  (256x128): scale * sum_d wq[i][h*32+d] * wk[c][h*32+d],  hc = h*64+c
//   wvo[o][hc]  (128x256): sum_d wv[c][h*32+d] * wo[h*32+d][o]
__global__ void prep_weights(const float* __restrict__ wq, const float* __restrict__ wk,
                             const float* __restrict__ wv, const float* __restrict__ wo,
                             u16* __restrict__ wqk, u16* __restrict__ wvo){
  int idx = blockIdx.x * 256 + threadIdx.x;   // 0..65535
  if (idx < 32768){
    int hc = idx >> 7, i = idx & 127;
    int h = hc >> 6, c = hc & 63;
    float acc = 0.f;
    #pragma unroll
    for (int d = 0; d < 32; ++d)
      acc += wq[i*128 + h*32 + d] * wk[c*128 + h*32 + d];
    wqk[idx] = f2b(acc * 0.17677669529663687f);  // 1/sqrt(32)
  } else {
    int j = idx - 32768;
    int o = j >> 8, hc = j & 255;
    int h = hc >> 6, c = hc & 63;
    float acc = 0.f;
    #pragma unroll
    for (int d = 0; d < 32; ++d)
      acc += wv[c*128 + h*32 + d] * wo[(h*32 + d)*128 + o];
    wvo[j] = f2b(acc);
  }
}

// Fused attention kernel (fp32 I/O, bf16 MFMA internals). Per 64-pixel tile:
//  P1: R = Z @ Wqk  (MFMA, B-frags streamed from L2-resident wqk)   -> LDS r bf16
//  P3a: logits = r . t_t (+mask bias), softmax
//  P3b: s = sum_t a_t*t_t -> LDS bf16 (ALIASES r region; barrier-protected)
//  P4: Out = S @ Wvo + bo (MFMA, B-frags streamed from L2)          -> fp32 staging (alias) -> store
// Single 32 KiB LDS region (r / s / staging time-share it) => 4 blocks/CU.
__global__ __launch_bounds__(256, 4)
void attn_main(const float* __restrict__ zp, const float* __restrict__ tp,
               const float* __restrict__ maskp, const float* __restrict__ bop,
               const u16* __restrict__ wqk, const u16* __restrict__ wvo,
               float* __restrict__ outp){
  extern __shared__ __align__(16) char smem[];
  u16*   sh16  = (u16*)smem;
  float* shf   = (float*)smem;
  uint4* sh128 = (uint4*)smem;   // 2048 uint4 units: r -> s -> fp32 out staging (aliased)

  const int tid  = threadIdx.x;
  const int w    = tid >> 6;
  const int lane = tid & 63;
  const int quad = lane >> 4;
  const int l16  = lane & 15;

  const v4f vzero = {0.f, 0.f, 0.f, 0.f};

  // ---- Phase 0: only tiny per-block state in registers (no persistent weight frags) ----
  float bof[2];
  #pragma unroll
  for (int n2 = 0; n2 < 2; ++n2) bof[n2] = bop[((w*2 + n2) << 4) | l16];
  float bias[4];
  #pragma unroll
  for (int tt = 0; tt < 4; ++tt) bias[tt] = 100000.0f * (maskp[tt] - 1.0f);

  for (int it = 0; it < TPW; ++it){
    const int tile = blockIdx.x + it * NWG;
    const long p0 = (long)tile * 64;

    // ---- P1: R-GEMM (A-frags from global fp32 z; B-frags streamed from wqk, L2-hot) ----
    v4f acc1[4][4];
    #pragma unroll
    for (int m = 0; m < 4; ++m)
      #pragma unroll
      for (int j = 0; j < 4; ++j) acc1[m][j] = vzero;
    #pragma unroll
    for (int ks = 0; ks < 4; ++ks){
      v8bf am[4];
      #pragma unroll
      for (int m = 0; m < 4; ++m){
        const float* zsrc = zp + (p0 + m*16 + l16)*128 + ks*32 + quad*8;
        v4f f0 = *(const v4f*)zsrc;
        v4f f1 = *(const v4f*)(zsrc + 4);
        union { v8bf v; u16 s[8]; } u;
        #pragma unroll
        for (int i = 0; i < 4; ++i){ u.s[i] = f2b(f0[i]); u.s[4+i] = f2b(f1[i]); }
        am[m] = u.v;
      }
      #pragma unroll
      for (int j = 0; j < 4; ++j){
        int hc = ((w*4 + j) << 4) | l16;
        v8bf bwf = *(const v8bf*)(wqk + hc*128 + ks*32 + quad*8);
        #pragma unroll
        for (int m = 0; m < 4; ++m)
          acc1[m][j] = __builtin_amdgcn_mfma_f32_16x16x32_bf16(am[m], bwf, acc1[m][j], 0, 0, 0);
      }
    }

    // ---- P2: C-frags -> LDS r bf16, unit=(hc>>3)*64+p, sub=(hc&7) ----
    #pragma unroll
    for (int m = 0; m < 4; ++m){
      #pragma unroll
      for (int j = 0; j < 4; ++j){
        int hc = ((w*4 + j) << 4) | l16;
        int unitbase = (hc >> 3)*64 + m*16 + quad*4;
        int cl = hc & 7;
        #pragma unroll
        for (int r = 0; r < 4; ++r)
          sh16[(unitbase + r)*8 + cl] = f2b(acc1[m][j][r]);
      }
    }
    __syncthreads();   // B1: r visible

    // ---- P3: logits (fp32 t), softmax over Nt=4, s = sum_t a_t*t_t -> LDS bf16 ----
    {
      const int h  = quad;            // lane = h*16 + psub; 64 px x 4 heads = 256 thr
      const int pl = (w << 4) | l16;  // local pixel 0..63
      const long gp = p0 + pl;
      const float* tb0 = tp + gp*64;  // template 0 row for this pixel
      float lg[4];
      #pragma unroll
      for (int tt = 0; tt < 4; ++tt) lg[tt] = bias[tt];
      #pragma unroll
      for (int cb = 0; cb < 8; ++cb){
        uint4 ru = sh128[(h*8 + cb)*64 + pl];
        const uint32* rr = (const uint32*)&ru;
        float rv[8];
        #pragma unroll
        for (int i = 0; i < 4; ++i){ rv[2*i] = bl(rr[i]); rv[2*i+1] = bh(rr[i]); }
        #pragma unroll
        for (int tt = 0; tt < 4; ++tt){
          const float* tsrc = tb0 + (long)tt*((long)NPIX*64) + cb*8;
          v4f ta = *(const v4f*)tsrc;
          v4f tb2 = *(const v4f*)(tsrc + 4);
          float a = lg[tt];
          a = fmaf(rv[0], ta[0], a);  a = fmaf(rv[1], ta[1], a);
          a = fmaf(rv[2], ta[2], a);  a = fmaf(rv[3], ta[3], a);
          a = fmaf(rv[4], tb2[0], a); a = fmaf(rv[5], tb2[1], a);
          a = fmaf(rv[6], tb2[2], a); a = fmaf(rv[7], tb2[3], a);
          lg[tt] = a;
        }
      }
      float mx = fmaxf(fmaxf(lg[0], lg[1]), fmaxf(lg[2], lg[3]));
      float e0 = __expf(lg[0]-mx), e1 = __expf(lg[1]-mx), e2 = __expf(lg[2]-mx), e3 = __expf(lg[3]-mx);
      float inv = 1.0f / (e0 + e1 + e2 + e3);
      float w0 = e0*inv, w1 = e1*inv, w2 = e2*inv, w3 = e3*inv;

      __syncthreads();   // B2: all threads done reading r -> region reusable for s

      #pragma unroll
      for (int cb = 0; cb < 8; ++cb){
        const float* t0s = tb0 + cb*8;                       // re-reads mostly hit L1/L2
        v4f a0 = *(const v4f*)t0s;                           v4f b0 = *(const v4f*)(t0s+4);
        v4f a1 = *(const v4f*)(t0s + (long)NPIX*64);         v4f b1 = *(const v4f*)(t0s + (long)NPIX*64 + 4);
        v4f a2 = *(const v4f*)(t0s + (long)NPIX*128);        v4f b2 = *(const v4f*)(t0s + (long)NPIX*128 + 4);
        v4f a3 = *(const v4f*)(t0s + (long)NPIX*192);        v4f b3 = *(const v4f*)(t0s + (long)NPIX*192 + 4);
        uint4 ov; uint32* op = (uint32*)&ov;
        #pragma unroll
        for (int i = 0; i < 2; ++i){
          float lo = w0*a0[2*i] + w1*a1[2*i] + w2*a2[2*i] + w3*a3[2*i];
          float hi = w0*a0[2*i+1] + w1*a1[2*i+1] + w2*a2[2*i+1] + w3*a3[2*i+1];
          op[i] = (uint32)f2b(lo) | (((uint32)f2b(hi)) << 16);
          float lo2 = w0*b0[2*i] + w1*b1[2*i] + w2*b2[2*i] + w3*b3[2*i];
          float hi2 = w0*b0[2*i+1] + w1*b1[2*i+1] + w2*b2[2*i+1] + w3*b3[2*i+1];
          op[2+i] = (uint32)f2b(lo2) | (((uint32)f2b(hi2)) << 16);
        }
        sh128[(h*8 + cb)*64 + pl] = ov;   // s aliases the dead r region
      }
    }
    __syncthreads();   // B3: s visible

    // ---- P4: Out-GEMM, A-frags from s chunks; B-frags streamed from wvo (L2-hot) ----
    v4f acc2[4][2];
    #pragma unroll
    for (int m = 0; m < 4; ++m){ acc2[m][0] = vzero; acc2[m][1] = vzero; }
    #pragma unroll
    for (int k8 = 0; k8 < 8; ++k8){
      v8bf a2[4];
      #pragma unroll
      for (int m = 0; m < 4; ++m)
        a2[m] = *(const v8bf*)&sh128[(k8*4 + quad)*64 + m*16 + l16];
      #pragma unroll
      for (int n2 = 0; n2 < 2; ++n2){
        int o = ((w*2 + n2) << 4) | l16;
        v8bf bwf2 = *(const v8bf*)(wvo + o*256 + k8*32 + quad*8);
        #pragma unroll
        for (int m = 0; m < 4; ++m)
          acc2[m][n2] = __builtin_amdgcn_mfma_f32_16x16x32_bf16(a2[m], bwf2, acc2[m][n2], 0, 0, 0);
      }
    }
    __syncthreads();   // B4: all threads done reading s -> region reusable for staging

    // ---- P5: epilogue (+bo) into fp32 out staging (aliases dead s region) ----
    #pragma unroll
    for (int m = 0; m < 4; ++m)
      #pragma unroll
      for (int n2 = 0; n2 < 2; ++n2){
        int ch = ((w*2 + n2) << 4) | l16;
        #pragma unroll
        for (int r = 0; r < 4; ++r){
          int pp = m*16 + quad*4 + r;
          shf[pp*128 + ch] = acc2[m][n2][r] + bof[n2];
        }
      }
    __syncthreads();   // B5: staging visible

    // ---- P6: coalesced fp32 store of 64 px x 128 ch (32KB) ----
    {
      uint4* og = (uint4*)(outp + p0*128);
      #pragma unroll
      for (int rep = 0; rep < 8; ++rep)
        og[rep*256 + tid] = sh128[rep*256 + tid];
    }
    __syncthreads();   // B6: staging free for next iter's P2
  }
}

extern "C" void kernel_launch(void* const* d_in, const int* in_sizes, int n_in,
                              void* d_out, int out_size, void* d_ws, size_t ws_size,
                              hipStream_t stream) {
  const float* t    = (const float*)d_in[0];
  const float* z    = (const float*)d_in[1];
  const float* mask = (const float*)d_in[2];
  const float* wq   = (const float*)d_in[3];
  const float* wk   = (const float*)d_in[4];
  const float* wv   = (const float*)d_in[5];
  const float* wo   = (const float*)d_in[6];
  const float* bo   = (const float*)d_in[7];
  float* out = (float*)d_out;

  u16* wqk = (u16*)d_ws;            // 256*128 bf16 = 64KB
  u16* wvo = wqk + 256*128;         // 128*256 bf16 = 64KB

  prep_weights<<<256, 256, 0, stream>>>(wq, wk, wv, wo, wqk, wvo);
  attn_main<<<NWG, 256, 32768, stream>>>(z, t, mask, bo, wqk, wvo, out);
}

// Round 2
// 1044.349 us; speedup vs baseline: 1.0039x; 1.0039x over previous
//
#include <hip/hip_runtime.h>

typedef unsigned int uint32;
typedef unsigned short u16;

#define NPIX (512*512)
#define NWG 2048
#define TPW 2   // NWG*TPW*64 == NPIX

typedef __bf16 v8bf __attribute__((ext_vector_type(8)));
typedef float v4f __attribute__((ext_vector_type(4)));

__device__ __forceinline__ float bl(uint32 u){ return __uint_as_float(u << 16); }
__device__ __forceinline__ float bh(uint32 u){ return __uint_as_float(u & 0xffff0000u); }
__device__ __forceinline__ u16 f2b(float f){
  uint32 u = __float_as_uint(f);
  u += 0x7fffu + ((u >> 16) & 1u);   // round-to-nearest-even
  return (u16)(u >> 16);
}

// Precompute fused weights (fp32 in, bf16 out) into workspace:
//   wqk[hc][i]  (256x128): scale * sum_d wq[i][h*32+d] * wk[c][h*32+d],  hc = h*64+c
//   wvo[o][hc]  (128x256): sum_d wv[c][h*32+d] * wo[h*32+d][o]
__global__ void prep_weights(const float* __restrict__ wq, const float* __restrict__ wk,
                             const float* __restrict__ wv, const float* __restrict__ wo,
                             u16* __restrict__ wqk, u16* __restrict__ wvo){
  int idx = blockIdx.x * 256 + threadIdx.x;   // 0..65535
  if (idx < 32768){
    int hc = idx >> 7, i = idx & 127;
    int h = hc >> 6, c = hc & 63;
    float acc = 0.f;
    #pragma unroll
    for (int d = 0; d < 32; ++d)
      acc += wq[i*128 + h*32 + d] * wk[c*128 + h*32 + d];
    wqk[idx] = f2b(acc * 0.17677669529663687f);  // 1/sqrt(32)
  } else {
    int j = idx - 32768;
    int o = j >> 8, hc = j & 255;
    int h = hc >> 6, c = hc & 63;
    float acc = 0.f;
    #pragma unroll
    for (int d = 0; d < 32; ++d)
      acc += wv[c*128 + h*32 + d] * wo[(h*32 + d)*128 + o];
    wvo[j] = f2b(acc);
  }
}

// Fused attention kernel (fp32 I/O, bf16 MFMA internals). Per 64-pixel tile:
//  P1: R = Z @ Wqk  (MFMA, M-split into 2 halves -> acc needs only 32 AGPR)
//      B-frags streamed from L2-resident wqk                         -> LDS r bf16
//  P3a: logits = r . t_t (+mask bias), softmax
//  P3b: s = sum_t a_t*t_t -> LDS bf16 (ALIASES r region; barrier-protected)
//  P4: Out = S @ Wvo + bo (MFMA, B-frags streamed from L2)           -> fp32 staging (alias) -> store
// Single 32 KiB LDS region + <=128 unified VGPR+AGPR => 4 blocks/CU, no scratch.
__global__ __launch_bounds__(256, 4)
void attn_main(const float* __restrict__ zp, const float* __restrict__ tp,
               const float* __restrict__ maskp, const float* __restrict__ bop,
               const u16* __restrict__ wqk, const u16* __restrict__ wvo,
               float* __restrict__ outp){
  extern __shared__ __align__(16) char smem[];
  u16*   sh16  = (u16*)smem;
  float* shf   = (float*)smem;
  uint4* sh128 = (uint4*)smem;   // 2048 uint4 units: r -> s -> fp32 out staging (aliased)

  const int tid  = threadIdx.x;
  const int w    = tid >> 6;
  const int lane = tid & 63;
  const int quad = lane >> 4;
  const int l16  = lane & 15;

  const v4f vzero = {0.f, 0.f, 0.f, 0.f};

  // ---- Phase 0: only tiny per-block state in registers ----
  float bof[2];
  #pragma unroll
  for (int n2 = 0; n2 < 2; ++n2) bof[n2] = bop[((w*2 + n2) << 4) | l16];
  float bias[4];
  #pragma unroll
  for (int tt = 0; tt < 4; ++tt) bias[tt] = 100000.0f * (maskp[tt] - 1.0f);

  for (int it = 0; it < TPW; ++it){
    const int tile = blockIdx.x + it * NWG;
    const long p0 = (long)tile * 64;

    // ---- P1: R-GEMM, M-split into two halves (acc = 2x4 frags = 32 AGPR) ----
    #pragma unroll
    for (int mh = 0; mh < 2; ++mh){
      v4f acc1[2][4];
      #pragma unroll
      for (int mm = 0; mm < 2; ++mm)
        #pragma unroll
        for (int j = 0; j < 4; ++j) acc1[mm][j] = vzero;
      #pragma unroll
      for (int ks = 0; ks < 4; ++ks){
        v8bf am[2];
        #pragma unroll
        for (int mm = 0; mm < 2; ++mm){
          const int m = mh*2 + mm;
          const float* zsrc = zp + (p0 + m*16 + l16)*128 + ks*32 + quad*8;
          v4f f0 = *(const v4f*)zsrc;
          v4f f1 = *(const v4f*)(zsrc + 4);
          union { v8bf v; u16 s[8]; } u;
          #pragma unroll
          for (int i = 0; i < 4; ++i){ u.s[i] = f2b(f0[i]); u.s[4+i] = f2b(f1[i]); }
          am[mm] = u.v;
        }
        #pragma unroll
        for (int j = 0; j < 4; ++j){
          int hc = ((w*4 + j) << 4) | l16;
          v8bf bwf = *(const v8bf*)(wqk + hc*128 + ks*32 + quad*8);
          #pragma unroll
          for (int mm = 0; mm < 2; ++mm)
            acc1[mm][j] = __builtin_amdgcn_mfma_f32_16x16x32_bf16(am[mm], bwf, acc1[mm][j], 0, 0, 0);
        }
      }
      // ---- P2 (per half): C-frags -> LDS r bf16, unit=(hc>>3)*64+p, sub=(hc&7) ----
      #pragma unroll
      for (int mm = 0; mm < 2; ++mm){
        const int m = mh*2 + mm;
        #pragma unroll
        for (int j = 0; j < 4; ++j){
          int hc = ((w*4 + j) << 4) | l16;
          int unitbase = (hc >> 3)*64 + m*16 + quad*4;
          int cl = hc & 7;
          #pragma unroll
          for (int r = 0; r < 4; ++r)
            sh16[(unitbase + r)*8 + cl] = f2b(acc1[mm][j][r]);
        }
      }
    }
    __syncthreads();   // B1: r visible

    // ---- P3: logits (fp32 t), softmax over Nt=4, s = sum_t a_t*t_t -> LDS bf16 ----
    {
      const int h  = quad;            // lane = h*16 + psub; 64 px x 4 heads = 256 thr
      const int pl = (w << 4) | l16;  // local pixel 0..63
      const long gp = p0 + pl;
      const float* tb0 = tp + gp*64;  // template 0 row for this pixel
      float lg[4];
      #pragma unroll
      for (int tt = 0; tt < 4; ++tt) lg[tt] = bias[tt];
      #pragma unroll
      for (int cb = 0; cb < 8; ++cb){
        uint4 ru = sh128[(h*8 + cb)*64 + pl];
        const uint32* rr = (const uint32*)&ru;
        float rv[8];
        #pragma unroll
        for (int i = 0; i < 4; ++i){ rv[2*i] = bl(rr[i]); rv[2*i+1] = bh(rr[i]); }
        #pragma unroll
        for (int tt = 0; tt < 4; ++tt){
          const float* tsrc = tb0 + (long)tt*((long)NPIX*64) + cb*8;
          v4f ta = *(const v4f*)tsrc;
          v4f tb2 = *(const v4f*)(tsrc + 4);
          float a = lg[tt];
          a = fmaf(rv[0], ta[0], a);  a = fmaf(rv[1], ta[1], a);
          a = fmaf(rv[2], ta[2], a);  a = fmaf(rv[3], ta[3], a);
          a = fmaf(rv[4], tb2[0], a); a = fmaf(rv[5], tb2[1], a);
          a = fmaf(rv[6], tb2[2], a); a = fmaf(rv[7], tb2[3], a);
          lg[tt] = a;
        }
      }
      float mx = fmaxf(fmaxf(lg[0], lg[1]), fmaxf(lg[2], lg[3]));
      float e0 = __expf(lg[0]-mx), e1 = __expf(lg[1]-mx), e2 = __expf(lg[2]-mx), e3 = __expf(lg[3]-mx);
      float inv = 1.0f / (e0 + e1 + e2 + e3);
      float w0 = e0*inv, w1 = e1*inv, w2 = e2*inv, w3 = e3*inv;

      __syncthreads();   // B2: all threads done reading r -> region reusable for s

      #pragma unroll
      for (int cb = 0; cb < 8; ++cb){
        const float* t0s = tb0 + cb*8;                       // re-reads mostly hit L1/L2
        v4f a0 = *(const v4f*)t0s;                           v4f b0 = *(const v4f*)(t0s+4);
        v4f a1 = *(const v4f*)(t0s + (long)NPIX*64);         v4f b1 = *(const v4f*)(t0s + (long)NPIX*64 + 4);
        v4f a2 = *(const v4f*)(t0s + (long)NPIX*128);        v4f b2 = *(const v4f*)(t0s + (long)NPIX*128 + 4);
        v4f a3 = *(const v4f*)(t0s + (long)NPIX*192);        v4f b3 = *(const v4f*)(t0s + (long)NPIX*192 + 4);
        uint4 ov; uint32* op = (uint32*)&ov;
        #pragma unroll
        for (int i = 0; i < 2; ++i){
          float lo = w0*a0[2*i] + w1*a1[2*i] + w2*a2[2*i] + w3*a3[2*i];
          float hi = w0*a0[2*i+1] + w1*a1[2*i+1] + w2*a2[2*i+1] + w3*a3[2*i+1];
          op[i] = (uint32)f2b(lo) | (((uint32)f2b(hi)) << 16);
          float lo2 = w0*b0[2*i] + w1*b1[2*i] + w2*b2[2*i] + w3*b3[2*i];
          float hi2 = w0*b0[2*i+1] + w1*b1[2*i+1] + w2*b2[2*i+1] + w3*b3[2*i+1];
          op[2+i] = (uint32)f2b(lo2) | (((uint32)f2b(hi2)) << 16);
        }
        sh128[(h*8 + cb)*64 + pl] = ov;   // s aliases the dead r region
      }
    }
    __syncthreads();   // B3: s visible

    // ---- P4: Out-GEMM, A-frags from s chunks; B-frags streamed from wvo (L2-hot) ----
    v4f acc2[4][2];
    #pragma unroll
    for (int m = 0; m < 4; ++m){ acc2[m][0] = vzero; acc2[m][1] = vzero; }
    #pragma unroll
    for (int k8 = 0; k8 < 8; ++k8){
      v8bf a2[4];
      #pragma unroll
      for (int m = 0; m < 4; ++m)
        a2[m] = *(const v8bf*)&sh128[(k8*4 + quad)*64 + m*16 + l16];
      #pragma unroll
      for (int n2 = 0; n2 < 2; ++n2){
        int o = ((w*2 + n2) << 4) | l16;
        v8bf bwf2 = *(const v8bf*)(wvo + o*256 + k8*32 + quad*8);
        #pragma unroll
        for (int m = 0; m < 4; ++m)
          acc2[m][n2] = __builtin_amdgcn_mfma_f32_16x16x32_bf16(a2[m], bwf2, acc2[m][n2], 0, 0, 0);
      }
    }
    __syncthreads();   // B4: all threads done reading s -> region reusable for staging

    // ---- P5: epilogue (+bo) into fp32 out staging (aliases dead s region) ----
    #pragma unroll
    for (int m = 0; m < 4; ++m)
      #pragma unroll
      for (int n2 = 0; n2 < 2; ++n2){
        int ch = ((w*2 + n2) << 4) | l16;
        #pragma unroll
        for (int r = 0; r < 4; ++r){
          int pp = m*16 + quad*4 + r;
          shf[pp*128 + ch] = acc2[m][n2][r] + bof[n2];
        }
      }
    __syncthreads();   // B5: staging visible

    // ---- P6: coalesced fp32 store of 64 px x 128 ch (32KB) ----
    {
      uint4* og = (uint4*)(outp + p0*128);
      #pragma unroll
      for (int rep = 0; rep < 8; ++rep)
        og[rep*256 + tid] = sh128[rep*256 + tid];
    }
    __syncthreads();   // B6: staging free for next iter's P2
  }
}

extern "C" void kernel_launch(void* const* d_in, const int* in_sizes, int n_in,
                              void* d_out, int out_size, void* d_ws, size_t ws_size,
                              hipStream_t stream) {
  const float* t    = (const float*)d_in[0];
  const float* z    = (const float*)d_in[1];
  const float* mask = (const float*)d_in[2];
  const float* wq   = (const float*)d_in[3];
  const float* wk   = (const float*)d_in[4];
  const float* wv   = (const float*)d_in[5];
  const float* wo   = (const float*)d_in[6];
  const float* bo   = (const float*)d_in[7];
  float* out = (float*)d_out;

  u16* wqk = (u16*)d_ws;            // 256*128 bf16 = 64KB
  u16* wvo = wqk + 256*128;         // 128*256 bf16 = 64KB

  prep_weights<<<256, 256, 0, stream>>>(wq, wk, wv, wo, wqk, wvo);
  attn_main<<<NWG, 256, 32768, stream>>>(z, t, mask, bo, wqk, wvo, out);
}

// Round 3
// 999.344 us; speedup vs baseline: 1.0491x; 1.0450x over previous
//
#include <hip/hip_runtime.h>

typedef unsigned int uint32;
typedef unsigned short u16;

#define NPIX (512*512)
#define NWG 2048
#define TPW 2   // NWG*TPW*64 == NPIX

typedef __bf16 v8bf __attribute__((ext_vector_type(8)));
typedef float v4f __attribute__((ext_vector_type(4)));

__device__ __forceinline__ float bl(uint32 u){ return __uint_as_float(u << 16); }
__device__ __forceinline__ float bh(uint32 u){ return __uint_as_float(u & 0xffff0000u); }
__device__ __forceinline__ u16 f2b(float f){
  uint32 u = __float_as_uint(f);
  u += 0x7fffu + ((u >> 16) & 1u);   // round-to-nearest-even
  return (u16)(u >> 16);
}

// Precompute fused weights (fp32 in, bf16 out) into workspace:
//   wqk[hc][i]  (256x128): scale * sum_d wq[i][h*32+d] * wk[c][h*32+d],  hc = h*64+c
//   wvo[o][hc]  (128x256): sum_d wv[c][h*32+d] * wo[h*32+d][o]
__global__ void prep_weights(const float* __restrict__ wq, const float* __restrict__ wk,
                             const float* __restrict__ wv, const float* __restrict__ wo,
                             u16* __restrict__ wqk, u16* __restrict__ wvo){
  int idx = blockIdx.x * 256 + threadIdx.x;   // 0..65535
  if (idx < 32768){
    int hc = idx >> 7, i = idx & 127;
    int h = hc >> 6, c = hc & 63;
    float acc = 0.f;
    #pragma unroll
    for (int d = 0; d < 32; ++d)
      acc += wq[i*128 + h*32 + d] * wk[c*128 + h*32 + d];
    wqk[idx] = f2b(acc * 0.17677669529663687f);  // 1/sqrt(32)
  } else {
    int j = idx - 32768;
    int o = j >> 8, hc = j & 255;
    int h = hc >> 6, c = hc & 63;
    float acc = 0.f;
    #pragma unroll
    for (int d = 0; d < 32; ++d)
      acc += wv[c*128 + h*32 + d] * wo[(h*32 + d)*128 + o];
    wvo[j] = f2b(acc);
  }
}

// Fused attention kernel (fp32 I/O, bf16 MFMA internals). Per 64-pixel tile:
//  P1: R = Z @ Wqk  (MFMA, B-frags streamed from L2-resident wqk)   -> LDS r bf16
//  P3a: logits = r . t_t (+mask bias), softmax
//  P3b: s = sum_t a_t*t_t -> LDS bf16 (ALIASES r region; barrier-protected)
//  P4: Out = S @ Wvo + bo (MFMA, B-frags streamed from L2)          -> fp32 staging (alias) -> store
// 32 KiB aliased LDS (r/s/staging time-share) + launch_bounds(256,3):
// reg cap ~170 (no spill, demand ~125) -> 3 blocks/CU (LDS would allow 5).
__global__ __launch_bounds__(256, 3)
void attn_main(const float* __restrict__ zp, const float* __restrict__ tp,
               const float* __restrict__ maskp, const float* __restrict__ bop,
               const u16* __restrict__ wqk, const u16* __restrict__ wvo,
               float* __restrict__ outp){
  extern __shared__ __align__(16) char smem[];
  u16*   sh16  = (u16*)smem;
  float* shf   = (float*)smem;
  uint4* sh128 = (uint4*)smem;   // 2048 uint4 units: r -> s -> fp32 out staging (aliased)

  const int tid  = threadIdx.x;
  const int w    = tid >> 6;
  const int lane = tid & 63;
  const int quad = lane >> 4;
  const int l16  = lane & 15;

  const v4f vzero = {0.f, 0.f, 0.f, 0.f};

  // ---- Phase 0: only tiny per-block state in registers ----
  float bof[2];
  #pragma unroll
  for (int n2 = 0; n2 < 2; ++n2) bof[n2] = bop[((w*2 + n2) << 4) | l16];
  float bias[4];
  #pragma unroll
  for (int tt = 0; tt < 4; ++tt) bias[tt] = 100000.0f * (maskp[tt] - 1.0f);

  for (int it = 0; it < TPW; ++it){
    const int tile = blockIdx.x + it * NWG;
    const long p0 = (long)tile * 64;

    // ---- P1: R-GEMM (A-frags from global fp32 z; B-frags streamed from wqk, L2-hot) ----
    v4f acc1[4][4];
    #pragma unroll
    for (int m = 0; m < 4; ++m)
      #pragma unroll
      for (int j = 0; j < 4; ++j) acc1[m][j] = vzero;
    #pragma unroll
    for (int ks = 0; ks < 4; ++ks){
      v8bf am[4];
      #pragma unroll
      for (int m = 0; m < 4; ++m){
        const float* zsrc = zp + (p0 + m*16 + l16)*128 + ks*32 + quad*8;
        v4f f0 = *(const v4f*)zsrc;
        v4f f1 = *(const v4f*)(zsrc + 4);
        union { v8bf v; u16 s[8]; } u;
        #pragma unroll
        for (int i = 0; i < 4; ++i){ u.s[i] = f2b(f0[i]); u.s[4+i] = f2b(f1[i]); }
        am[m] = u.v;
      }
      #pragma unroll
      for (int j = 0; j < 4; ++j){
        int hc = ((w*4 + j) << 4) | l16;
        v8bf bwf = *(const v8bf*)(wqk + hc*128 + ks*32 + quad*8);
        #pragma unroll
        for (int m = 0; m < 4; ++m)
          acc1[m][j] = __builtin_amdgcn_mfma_f32_16x16x32_bf16(am[m], bwf, acc1[m][j], 0, 0, 0);
      }
    }

    // ---- P2: C-frags -> LDS r bf16, unit=(hc>>3)*64+p, sub=(hc&7) ----
    #pragma unroll
    for (int m = 0; m < 4; ++m){
      #pragma unroll
      for (int j = 0; j < 4; ++j){
        int hc = ((w*4 + j) << 4) | l16;
        int unitbase = (hc >> 3)*64 + m*16 + quad*4;
        int cl = hc & 7;
        #pragma unroll
        for (int r = 0; r < 4; ++r)
          sh16[(unitbase + r)*8 + cl] = f2b(acc1[m][j][r]);
      }
    }
    __syncthreads();   // B1: r visible

    // ---- P3: logits (fp32 t), softmax over Nt=4, s = sum_t a_t*t_t -> LDS bf16 ----
    {
      const int h  = quad;            // lane = h*16 + psub; 64 px x 4 heads = 256 thr
      const int pl = (w << 4) | l16;  // local pixel 0..63
      const long gp = p0 + pl;
      const float* tb0 = tp + gp*64;  // template 0 row for this pixel
      float lg[4];
      #pragma unroll
      for (int tt = 0; tt < 4; ++tt) lg[tt] = bias[tt];
      #pragma unroll
      for (int cb = 0; cb < 8; ++cb){
        uint4 ru = sh128[(h*8 + cb)*64 + pl];
        const uint32* rr = (const uint32*)&ru;
        float rv[8];
        #pragma unroll
        for (int i = 0; i < 4; ++i){ rv[2*i] = bl(rr[i]); rv[2*i+1] = bh(rr[i]); }
        #pragma unroll
        for (int tt = 0; tt < 4; ++tt){
          const float* tsrc = tb0 + (long)tt*((long)NPIX*64) + cb*8;
          v4f ta = *(const v4f*)tsrc;
          v4f tb2 = *(const v4f*)(tsrc + 4);
          float a = lg[tt];
          a = fmaf(rv[0], ta[0], a);  a = fmaf(rv[1], ta[1], a);
          a = fmaf(rv[2], ta[2], a);  a = fmaf(rv[3], ta[3], a);
          a = fmaf(rv[4], tb2[0], a); a = fmaf(rv[5], tb2[1], a);
          a = fmaf(rv[6], tb2[2], a); a = fmaf(rv[7], tb2[3], a);
          lg[tt] = a;
        }
      }
      float mx = fmaxf(fmaxf(lg[0], lg[1]), fmaxf(lg[2], lg[3]));
      float e0 = __expf(lg[0]-mx), e1 = __expf(lg[1]-mx), e2 = __expf(lg[2]-mx), e3 = __expf(lg[3]-mx);
      float inv = 1.0f / (e0 + e1 + e2 + e3);
      float w0 = e0*inv, w1 = e1*inv, w2 = e2*inv, w3 = e3*inv;

      __syncthreads();   // B2: all threads done reading r -> region reusable for s

      #pragma unroll
      for (int cb = 0; cb < 8; ++cb){
        const float* t0s = tb0 + cb*8;                       // re-reads mostly hit L1/L2/L3
        v4f a0 = *(const v4f*)t0s;                           v4f b0 = *(const v4f*)(t0s+4);
        v4f a1 = *(const v4f*)(t0s + (long)NPIX*64);         v4f b1 = *(const v4f*)(t0s + (long)NPIX*64 + 4);
        v4f a2 = *(const v4f*)(t0s + (long)NPIX*128);        v4f b2 = *(const v4f*)(t0s + (long)NPIX*128 + 4);
        v4f a3 = *(const v4f*)(t0s + (long)NPIX*192);        v4f b3 = *(const v4f*)(t0s + (long)NPIX*192 + 4);
        uint4 ov; uint32* op = (uint32*)&ov;
        #pragma unroll
        for (int i = 0; i < 2; ++i){
          float lo = w0*a0[2*i] + w1*a1[2*i] + w2*a2[2*i] + w3*a3[2*i];
          float hi = w0*a0[2*i+1] + w1*a1[2*i+1] + w2*a2[2*i+1] + w3*a3[2*i+1];
          op[i] = (uint32)f2b(lo) | (((uint32)f2b(hi)) << 16);
          float lo2 = w0*b0[2*i] + w1*b1[2*i] + w2*b2[2*i] + w3*b3[2*i];
          float hi2 = w0*b0[2*i+1] + w1*b1[2*i+1] + w2*b2[2*i+1] + w3*b3[2*i+1];
          op[2+i] = (uint32)f2b(lo2) | (((uint32)f2b(hi2)) << 16);
        }
        sh128[(h*8 + cb)*64 + pl] = ov;   // s aliases the dead r region
      }
    }
    __syncthreads();   // B3: s visible

    // ---- P4: Out-GEMM, A-frags from s chunks; B-frags streamed from wvo (L2-hot) ----
    v4f acc2[4][2];
    #pragma unroll
    for (int m = 0; m < 4; ++m){ acc2[m][0] = vzero; acc2[m][1] = vzero; }
    #pragma unroll
    for (int k8 = 0; k8 < 8; ++k8){
      v8bf a2[4];
      #pragma unroll
      for (int m = 0; m < 4; ++m)
        a2[m] = *(const v8bf*)&sh128[(k8*4 + quad)*64 + m*16 + l16];
      #pragma unroll
      for (int n2 = 0; n2 < 2; ++n2){
        int o = ((w*2 + n2) << 4) | l16;
        v8bf bwf2 = *(const v8bf*)(wvo + o*256 + k8*32 + quad*8);
        #pragma unroll
        for (int m = 0; m < 4; ++m)
          acc2[m][n2] = __builtin_amdgcn_mfma_f32_16x16x32_bf16(a2[m], bwf2, acc2[m][n2], 0, 0, 0);
      }
    }
    __syncthreads();   // B4: all threads done reading s -> region reusable for staging

    // ---- P5: epilogue (+bo) into fp32 out staging (aliases dead s region) ----
    #pragma unroll
    for (int m = 0; m < 4; ++m)
      #pragma unroll
      for (int n2 = 0; n2 < 2; ++n2){
        int ch = ((w*2 + n2) << 4) | l16;
        #pragma unroll
        for (int r = 0; r < 4; ++r){
          int pp = m*16 + quad*4 + r;
          shf[pp*128 + ch] = acc2[m][n2][r] + bof[n2];
        }
      }
    __syncthreads();   // B5: staging visible

    // ---- P6: coalesced fp32 store of 64 px x 128 ch (32KB) ----
    {
      uint4* og = (uint4*)(outp + p0*128);
      #pragma unroll
      for (int rep = 0; rep < 8; ++rep)
        og[rep*256 + tid] = sh128[rep*256 + tid];
    }
    __syncthreads();   // B6: staging free for next iter's P2
  }
}

extern "C" void kernel_launch(void* const* d_in, const int* in_sizes, int n_in,
                              void* d_out, int out_size, void* d_ws, size_t ws_size,
                              hipStream_t stream) {
  const float* t    = (const float*)d_in[0];
  const float* z    = (const float*)d_in[1];
  const float* mask = (const float*)d_in[2];
  const float* wq   = (const float*)d_in[3];
  const float* wk   = (const float*)d_in[4];
  const float* wv   = (const float*)d_in[5];
  const float* wo   = (const float*)d_in[6];
  const float* bo   = (const float*)d_in[7];
  float* out = (float*)d_out;

  u16* wqk = (u16*)d_ws;            // 256*128 bf16 = 64KB
  u16* wvo = wqk + 256*128;         // 128*256 bf16 = 64KB

  prep_weights<<<256, 256, 0, stream>>>(wq, wk, wv, wo, wqk, wvo);
  attn_main<<<NWG, 256, 32768, stream>>>(z, t, mask, bo, wqk, wvo, out);
}

// Round 4
// 748.799 us; speedup vs baseline: 1.4001x; 1.3346x over previous
//
#include <hip/hip_runtime.h>

typedef unsigned int uint32;
typedef unsigned short u16;

#define NPIX (512*512)
#define NWG 2048
#define TPW 2   // NWG*TPW*64 == NPIX

typedef __bf16 v8bf __attribute__((ext_vector_type(8)));
typedef float v4f __attribute__((ext_vector_type(4)));

__device__ __forceinline__ float bl(uint32 u){ return __uint_as_float(u << 16); }
__device__ __forceinline__ float bh(uint32 u){ return __uint_as_float(u & 0xffff0000u); }
__device__ __forceinline__ u16 f2b(float f){
  uint32 u = __float_as_uint(f);
  u += 0x7fffu + ((u >> 16) & 1u);   // round-to-nearest-even
  return (u16)(u >> 16);
}

// Precompute fused weights (fp32 in, bf16 out) into workspace:
//   wqk[hc][i]  (256x128): scale * sum_d wq[i][h*32+d] * wk[c][h*32+d],  hc = h*64+c
//   wvo[o][hc]  (128x256): sum_d wv[c][h*32+d] * wo[h*32+d][o]
__global__ void prep_weights(const float* __restrict__ wq, const float* __restrict__ wk,
                             const float* __restrict__ wv, const float* __restrict__ wo,
                             u16* __restrict__ wqk, u16* __restrict__ wvo){
  int idx = blockIdx.x * 256 + threadIdx.x;   // 0..65535
  if (idx < 32768){
    int hc = idx >> 7, i = idx & 127;
    int h = hc >> 6, c = hc & 63;
    float acc = 0.f;
    #pragma unroll
    for (int d = 0; d < 32; ++d)
      acc += wq[i*128 + h*32 + d] * wk[c*128 + h*32 + d];
    wqk[idx] = f2b(acc * 0.17677669529663687f);  // 1/sqrt(32)
  } else {
    int j = idx - 32768;
    int o = j >> 8, hc = j & 255;
    int h = hc >> 6, c = hc & 63;
    float acc = 0.f;
    #pragma unroll
    for (int d = 0; d < 32; ++d)
      acc += wv[c*128 + h*32 + d] * wo[(h*32 + d)*128 + o];
    wvo[j] = f2b(acc);
  }
}

// Fused attention kernel (fp32 I/O, bf16 MFMA internals). Per 64-pixel tile:
//  P1: R = Z @ Wqk  (MFMA, two sequential M-halves, acc = 32 AGPR live) -> LDS r bf16
//  P3a: logits = r . t_t (+mask bias), softmax
//  P3b: s = sum_t a_t*t_t -> LDS bf16 (ALIASES r region; barrier-protected)
//  P4: Out = S @ Wvo + bo (MFMA, B-frags streamed from L2)  -> fp32 staging (alias) -> store
// Register discipline: every load loop has bounded unroll (<=2) so the scheduler
// can't hoist 64 independent loads and spill. Target: 3 blocks/CU, zero scratch.
__global__ __launch_bounds__(256, 3)
void attn_main(const float* __restrict__ zp, const float* __restrict__ tp,
               const float* __restrict__ maskp, const float* __restrict__ bop,
               const u16* __restrict__ wqk, const u16* __restrict__ wvo,
               float* __restrict__ outp){
  extern __shared__ __align__(16) char smem[];
  u16*   sh16  = (u16*)smem;
  float* shf   = (float*)smem;
  uint4* sh128 = (uint4*)smem;   // 2048 uint4 units: r -> s -> fp32 out staging (aliased)

  const int tid  = threadIdx.x;
  const int w    = tid >> 6;
  const int lane = tid & 63;
  const int quad = lane >> 4;
  const int l16  = lane & 15;

  const v4f vzero = {0.f, 0.f, 0.f, 0.f};

  // ---- Phase 0: only tiny per-block state in registers ----
  float bof[2];
  #pragma unroll
  for (int n2 = 0; n2 < 2; ++n2) bof[n2] = bop[((w*2 + n2) << 4) | l16];
  float bias[4];
  #pragma unroll
  for (int tt = 0; tt < 4; ++tt) bias[tt] = 100000.0f * (maskp[tt] - 1.0f);

  for (int it = 0; it < TPW; ++it){
    const int tile = blockIdx.x + it * NWG;
    const long p0 = (long)tile * 64;

    // ---- P1: R-GEMM, two SEQUENTIAL M-halves (unroll 1 is load-pressure control) ----
    #pragma unroll 1
    for (int mh = 0; mh < 2; ++mh){
      v4f acc1[2][4];
      #pragma unroll
      for (int mm = 0; mm < 2; ++mm)
        #pragma unroll
        for (int j = 0; j < 4; ++j) acc1[mm][j] = vzero;
      #pragma unroll 2
      for (int ks = 0; ks < 4; ++ks){
        v8bf am[2];
        #pragma unroll
        for (int mm = 0; mm < 2; ++mm){
          const int m = mh*2 + mm;
          const float* zsrc = zp + (p0 + m*16 + l16)*128 + ks*32 + quad*8;
          v4f f0 = *(const v4f*)zsrc;
          v4f f1 = *(const v4f*)(zsrc + 4);
          union { v8bf v; u16 s[8]; } u;
          #pragma unroll
          for (int i = 0; i < 4; ++i){ u.s[i] = f2b(f0[i]); u.s[4+i] = f2b(f1[i]); }
          am[mm] = u.v;
        }
        #pragma unroll
        for (int j = 0; j < 4; ++j){
          int hc = ((w*4 + j) << 4) | l16;
          v8bf bwf = *(const v8bf*)(wqk + hc*128 + ks*32 + quad*8);
          #pragma unroll
          for (int mm = 0; mm < 2; ++mm)
            acc1[mm][j] = __builtin_amdgcn_mfma_f32_16x16x32_bf16(am[mm], bwf, acc1[mm][j], 0, 0, 0);
        }
      }
      // ---- P2 (this half): C-frags -> LDS r bf16, unit=(hc>>3)*64+p, sub=(hc&7) ----
      #pragma unroll
      for (int mm = 0; mm < 2; ++mm){
        const int m = mh*2 + mm;
        #pragma unroll
        for (int j = 0; j < 4; ++j){
          int hc = ((w*4 + j) << 4) | l16;
          int unitbase = (hc >> 3)*64 + m*16 + quad*4;
          int cl = hc & 7;
          #pragma unroll
          for (int r = 0; r < 4; ++r)
            sh16[(unitbase + r)*8 + cl] = f2b(acc1[mm][j][r]);
        }
      }
    }
    __syncthreads();   // B1: r visible

    // ---- P3: logits (fp32 t), softmax over Nt=4, s = sum_t a_t*t_t -> LDS bf16 ----
    {
      const int h  = quad;            // lane = h*16 + psub; 64 px x 4 heads = 256 thr
      const int pl = (w << 4) | l16;  // local pixel 0..63
      const long gp = p0 + pl;
      const float* tb0 = tp + gp*64;  // template 0 row for this pixel
      float lg[4];
      #pragma unroll
      for (int tt = 0; tt < 4; ++tt) lg[tt] = bias[tt];
      #pragma unroll 2
      for (int cb = 0; cb < 8; ++cb){
        uint4 ru = sh128[(h*8 + cb)*64 + pl];
        const uint32* rr = (const uint32*)&ru;
        float rv[8];
        #pragma unroll
        for (int i = 0; i < 4; ++i){ rv[2*i] = bl(rr[i]); rv[2*i+1] = bh(rr[i]); }
        #pragma unroll
        for (int tt = 0; tt < 4; ++tt){
          const float* tsrc = tb0 + (long)tt*((long)NPIX*64) + cb*8;
          v4f ta = *(const v4f*)tsrc;
          v4f tb2 = *(const v4f*)(tsrc + 4);
          float a = lg[tt];
          a = fmaf(rv[0], ta[0], a);  a = fmaf(rv[1], ta[1], a);
          a = fmaf(rv[2], ta[2], a);  a = fmaf(rv[3], ta[3], a);
          a = fmaf(rv[4], tb2[0], a); a = fmaf(rv[5], tb2[1], a);
          a = fmaf(rv[6], tb2[2], a); a = fmaf(rv[7], tb2[3], a);
          lg[tt] = a;
        }
      }
      float mx = fmaxf(fmaxf(lg[0], lg[1]), fmaxf(lg[2], lg[3]));
      float e0 = __expf(lg[0]-mx), e1 = __expf(lg[1]-mx), e2 = __expf(lg[2]-mx), e3 = __expf(lg[3]-mx);
      float inv = 1.0f / (e0 + e1 + e2 + e3);
      float w0 = e0*inv, w1 = e1*inv, w2 = e2*inv, w3 = e3*inv;

      __syncthreads();   // B2: all threads done reading r -> region reusable for s

      #pragma unroll 2
      for (int cb = 0; cb < 8; ++cb){
        const float* t0s = tb0 + cb*8;                       // re-reads mostly hit L1/L2/L3
        v4f a0 = *(const v4f*)t0s;                           v4f b0 = *(const v4f*)(t0s+4);
        v4f a1 = *(const v4f*)(t0s + (long)NPIX*64);         v4f b1 = *(const v4f*)(t0s + (long)NPIX*64 + 4);
        v4f a2 = *(const v4f*)(t0s + (long)NPIX*128);        v4f b2 = *(const v4f*)(t0s + (long)NPIX*128 + 4);
        v4f a3 = *(const v4f*)(t0s + (long)NPIX*192);        v4f b3 = *(const v4f*)(t0s + (long)NPIX*192 + 4);
        uint4 ov; uint32* op = (uint32*)&ov;
        #pragma unroll
        for (int i = 0; i < 2; ++i){
          float lo = w0*a0[2*i] + w1*a1[2*i] + w2*a2[2*i] + w3*a3[2*i];
          float hi = w0*a0[2*i+1] + w1*a1[2*i+1] + w2*a2[2*i+1] + w3*a3[2*i+1];
          op[i] = (uint32)f2b(lo) | (((uint32)f2b(hi)) << 16);
          float lo2 = w0*b0[2*i] + w1*b1[2*i] + w2*b2[2*i] + w3*b3[2*i];
          float hi2 = w0*b0[2*i+1] + w1*b1[2*i+1] + w2*b2[2*i+1] + w3*b3[2*i+1];
          op[2+i] = (uint32)f2b(lo2) | (((uint32)f2b(hi2)) << 16);
        }
        sh128[(h*8 + cb)*64 + pl] = ov;   // s aliases the dead r region
      }
    }
    __syncthreads();   // B3: s visible

    // ---- P4: Out-GEMM, A-frags from s chunks; B-frags streamed from wvo (L2-hot) ----
    v4f acc2[4][2];
    #pragma unroll
    for (int m = 0; m < 4; ++m){ acc2[m][0] = vzero; acc2[m][1] = vzero; }
    #pragma unroll 2
    for (int k8 = 0; k8 < 8; ++k8){
      v8bf a2[4];
      #pragma unroll
      for (int m = 0; m < 4; ++m)
        a2[m] = *(const v8bf*)&sh128[(k8*4 + quad)*64 + m*16 + l16];
      #pragma unroll
      for (int n2 = 0; n2 < 2; ++n2){
        int o = ((w*2 + n2) << 4) | l16;
        v8bf bwf2 = *(const v8bf*)(wvo + o*256 + k8*32 + quad*8);
        #pragma unroll
        for (int m = 0; m < 4; ++m)
          acc2[m][n2] = __builtin_amdgcn_mfma_f32_16x16x32_bf16(a2[m], bwf2, acc2[m][n2], 0, 0, 0);
      }
    }
    __syncthreads();   // B4: all threads done reading s -> region reusable for staging

    // ---- P5: epilogue (+bo) into fp32 out staging (aliases dead s region) ----
    #pragma unroll
    for (int m = 0; m < 4; ++m)
      #pragma unroll
      for (int n2 = 0; n2 < 2; ++n2){
        int ch = ((w*2 + n2) << 4) | l16;
        #pragma unroll
        for (int r = 0; r < 4; ++r){
          int pp = m*16 + quad*4 + r;
          shf[pp*128 + ch] = acc2[m][n2][r] + bof[n2];
        }
      }
    __syncthreads();   // B5: staging visible

    // ---- P6: coalesced fp32 store of 64 px x 128 ch (32KB) ----
    {
      uint4* og = (uint4*)(outp + p0*128);
      #pragma unroll
      for (int rep = 0; rep < 8; ++rep)
        og[rep*256 + tid] = sh128[rep*256 + tid];
    }
    __syncthreads();   // B6: staging free for next iter's P2
  }
}

extern "C" void kernel_launch(void* const* d_in, const int* in_sizes, int n_in,
                              void* d_out, int out_size, void* d_ws, size_t ws_size,
                              hipStream_t stream) {
  const float* t    = (const float*)d_in[0];
  const float* z    = (const float*)d_in[1];
  const float* mask = (const float*)d_in[2];
  const float* wq   = (const float*)d_in[3];
  const float* wk   = (const float*)d_in[4];
  const float* wv   = (const float*)d_in[5];
  const float* wo   = (const float*)d_in[6];
  const float* bo   = (const float*)d_in[7];
  float* out = (float*)d_out;

  u16* wqk = (u16*)d_ws;            // 256*128 bf16 = 64KB
  u16* wvo = wqk + 256*128;         // 128*256 bf16 = 64KB

  prep_weights<<<256, 256, 0, stream>>>(wq, wk, wv, wo, wqk, wvo);
  attn_main<<<NWG, 256, 32768, stream>>>(z, t, mask, bo, wqk, wvo, out);
}